// Round 10
// baseline (499.409 us; speedup 1.0000x reference)
//
#include <hip/hip_runtime.h>
#include <math.h>

#define T  512                     // 8-wave blocks
#define TP 1024                    // prep kernels keep 1024 threads
#define PS 1156                    // 34*34 plane

#define ZSZ (4 * 5 * 1024 * 4)     // Z[quad g][j][pix] as float4 (floats)
// fcwT at ws + ZSZ: 8192 float4. total ws = 448 KB

// ---- scalar conv accumulate (known-good codegen) ----
template <int NIC, int NOC, int WSTR>
__device__ __forceinline__ void conv_acc(const float* __restrict__ ib,
                                         const float* __restrict__ wg,
                                         float* __restrict__ acc) {
#pragma unroll 2
    for (int ic = 0; ic < NIC; ++ic) {
        float v[9];
#pragma unroll
        for (int ky = 0; ky < 3; ++ky)
#pragma unroll
            for (int kx = 0; kx < 3; ++kx)
                v[ky * 3 + kx] = ib[ic * PS + ky * 34 + kx];
#pragma unroll
        for (int oc = 0; oc < NOC; ++oc) {
            const float* wp = wg + oc * WSTR + ic * 9;
#pragma unroll
            for (int k = 0; k < 9; ++k)
                acc[oc] = fmaf(wp[k], v[k], acc[oc]);
        }
    }
}

// ---- channel-quad conv accumulate: 4 channels in float4 lanes, NOC outputs ----
template <int NOC, int WSTR>
__device__ __forceinline__ void conv_q4(const float4* __restrict__ ib,
                                        const float* __restrict__ wg,
                                        float* __restrict__ acc) {
#pragma unroll
    for (int ky = 0; ky < 3; ++ky) {
        const float4 r0 = ib[ky * 34 + 0];
        const float4 r1 = ib[ky * 34 + 1];
        const float4 r2 = ib[ky * 34 + 2];
#pragma unroll
        for (int oc = 0; oc < NOC; ++oc) {
            const float* wp = wg + oc * WSTR + ky * 3;   // uniform -> s_load
            float s = acc[oc];
            s = fmaf(wp[0],  r0.x, s); s = fmaf(wp[1],  r1.x, s); s = fmaf(wp[2],  r2.x, s);
            s = fmaf(wp[9],  r0.y, s); s = fmaf(wp[10], r1.y, s); s = fmaf(wp[11], r2.y, s);
            s = fmaf(wp[18], r0.z, s); s = fmaf(wp[19], r1.z, s); s = fmaf(wp[20], r2.z, s);
            s = fmaf(wp[27], r0.w, s); s = fmaf(wp[28], r1.w, s); s = fmaf(wp[29], r2.w, s);
            acc[oc] = s;
        }
    }
}

// ---- prep 1: decoder basis Z[g][j][pix] = conv3x3(F_j, d1w) (+d1b for j=4) ----
__global__ __launch_bounds__(TP) void prep_z_kernel(
    const float* __restrict__ f2w, const float* __restrict__ f2b,
    const float* __restrict__ d1w, const float* __restrict__ d1b,
    float* __restrict__ ws) {
    __shared__ float F[8 * PS];
    const int tid = threadIdx.x;
    const int j = blockIdx.x;                 // 0..4 (4 = bias basis)
    const int py = tid >> 5, px = tid & 31;
    const int wbase = py * 34 + px;
    const int ibase = (py + 1) * 34 + (px + 1);

    for (int i = tid; i < 8 * PS; i += TP) F[i] = 0.f;
    __syncthreads();
#pragma unroll
    for (int c = 0; c < 8; ++c) {
        const int idx = c * 1024 + tid;
        F[c * PS + ibase] = (j < 4) ? f2w[idx * 4 + j] : f2b[idx];
    }
    __syncthreads();
    float a1[16];
#pragma unroll
    for (int oc = 0; oc < 16; ++oc) a1[oc] = (j == 4) ? d1b[oc] : 0.f;
    conv_acc<8, 16, 72>(F + wbase, d1w, a1);
#pragma unroll
    for (int g = 0; g < 4; ++g) {
        float4 v = make_float4(a1[4 * g], a1[4 * g + 1], a1[4 * g + 2], a1[4 * g + 3]);
        *reinterpret_cast<float4*>(ws + ((g * 5 + j) * 1024 + tid) * 4) = v;
    }
}

// ---- prep 2: fcwT[gj] = float4{fcw[o*8192+gj]} ----
__global__ __launch_bounds__(TP) void prep_fcwt_kernel(
    const float* __restrict__ fcw, float* __restrict__ fcwT) {
    const int i = blockIdx.x * TP + threadIdx.x;
#pragma unroll
    for (int o = 0; o < 4; ++o)
        fcwT[i * 4 + o] = fcw[o * 8192 + i];
}

// ---------------- fused per-image kernel -----------------------------------
// T=512, LB(512,4): VGPR cap 128 (the one proven non-spilling setting).
// LDS 51.7 KB/block -> up to 3 blocks/CU (155 KB) if VGPR <= 85.
__global__ __launch_bounds__(T, 4) void fused_kernel(
    const float* __restrict__ x,
    const float* __restrict__ c1w, const float* __restrict__ c1b,
    const float* __restrict__ c2w, const float* __restrict__ c2b,
    const float* __restrict__ fcb,
    const float* __restrict__ qw,
    const float* __restrict__ d2w, const float* __restrict__ d2b,
    const float* __restrict__ ws,
    float* __restrict__ out) {
    __shared__ float  XS[3 * PS];     // x, scalar planes (conv1 is cheap)
    __shared__ float4 BQ[2 * PS];     // h1/h4 channel-quad halves
    __shared__ float  SM[168];        // ROT 96 | ANG 4 | Q 4 | RED 32
    float* ROT = SM;
    const float* fcwT = ws + ZSZ;

    const int tid = threadIdx.x;
    const int b   = blockIdx.x;
    const int px  = tid & 31;
    const int py0 = tid >> 5;         // rows 0..15 ; second pixel = +16 rows

    const float4 z4 = make_float4(0.f, 0.f, 0.f, 0.f);
    for (int i = tid; i < 3 * PS; i += T) XS[i] = 0.f;      // halos must be 0
    for (int i = tid; i < 2 * PS; i += T) BQ[i] = z4;
    if (tid < 168) SM[tid] = 0.f;
    __syncthreads();

    if (tid < 12) {   // Rot matrices (batch-independent, tiny)
        float phi = qw[tid * 3 + 0], theta = qw[tid * 3 + 1], omega = qw[tid * 3 + 2];
        float a = 0.5f * (phi + omega), d = 0.5f * (phi - omega);
        float st, ct; sincosf(0.5f * theta, &st, &ct);
        float sa, ca; sincosf(a, &sa, &ca);
        float sd, cd; sincosf(d, &sd, &cd);
        float* o = ROT + tid * 8;
        o[0] = ct * ca;  o[1] = -ct * sa;
        o[2] = -st * cd; o[3] = -st * sd;
        o[4] = st * cd;  o[5] = -st * sd;
        o[6] = ct * ca;  o[7] = ct * sa;
    }

    // ---- load x (3,32,32) into XS interior: 6 elems/thread ----
    {
        const float* xb = x + b * 3072;
#pragma unroll
        for (int k = 0; k < 6; ++k) {
            int i = tid + k * T;
            int c = i >> 10, p = i & 1023;
            XS[c * PS + ((p >> 5) + 1) * 34 + (p & 31) + 1] = xb[i];
        }
    }
    __syncthreads();

    float acc2[2][8];                 // conv2 accumulators, both pixels
#pragma unroll
    for (int pp = 0; pp < 2; ++pp)
#pragma unroll
        for (int oc = 0; oc < 8; ++oc) acc2[pp][oc] = c2b[oc];
    float part[4] = {0.f, 0.f, 0.f, 0.f};

#pragma unroll
    for (int h = 0; h < 2; ++h) {
        // ---- conv1 half h -> BQ quads (both pixels, sequential) ----
#pragma unroll
        for (int pp = 0; pp < 2; ++pp) {
            const int py = py0 + pp * 16;
            const int wb = py * 34 + px, ibs = (py + 1) * 34 + (px + 1);
            float a1[8];
#pragma unroll
            for (int oc = 0; oc < 8; ++oc) a1[oc] = c1b[h * 8 + oc];
            conv_acc<3, 8, 27>(XS + wb, c1w + h * 8 * 27, a1);
            BQ[ibs]      = make_float4(fmaxf(a1[0], 0.f), fmaxf(a1[1], 0.f),
                                       fmaxf(a1[2], 0.f), fmaxf(a1[3], 0.f));
            BQ[PS + ibs] = make_float4(fmaxf(a1[4], 0.f), fmaxf(a1[5], 0.f),
                                       fmaxf(a1[6], 0.f), fmaxf(a1[7], 0.f));
        }
        __syncthreads();
        // ---- conv2 partial over this half's 8 input channels (both px) ----
#pragma unroll
        for (int pp = 0; pp < 2; ++pp) {
            const int wb = (py0 + pp * 16) * 34 + px;
            conv_q4<8, 144>(BQ + wb,      c2w + (h * 8 + 0) * 9, acc2[pp]);
            conv_q4<8, 144>(BQ + PS + wb, c2w + (h * 8 + 4) * 9, acc2[pp]);
        }
        __syncthreads();   // before next half overwrites BQ
    }

    // ---- relu + fc fold (float4 fcwT), both pixels ----
#pragma unroll
    for (int pp = 0; pp < 2; ++pp) {
        const int p = tid + pp * T;
#pragma unroll
        for (int oc = 0; oc < 8; ++oc) {
            const float hv = fmaxf(acc2[pp][oc], 0.f);
            const float4 wv = *reinterpret_cast<const float4*>(fcwT + (oc * 1024 + p) * 4);
            part[0] = fmaf(hv, wv.x, part[0]);
            part[1] = fmaf(hv, wv.y, part[1]);
            part[2] = fmaf(hv, wv.z, part[2]);
            part[3] = fmaf(hv, wv.w, part[3]);
        }
    }

    // ---- fc reduce -> angles (8 waves) ----
#pragma unroll
    for (int off = 32; off; off >>= 1)
#pragma unroll
        for (int o = 0; o < 4; ++o)
            part[o] += __shfl_down(part[o], off);
    if ((tid & 63) == 0) {
        int wid = tid >> 6;
#pragma unroll
        for (int o = 0; o < 4; ++o) SM[104 + wid * 4 + o] = part[o];
    }
    __syncthreads();
    if (tid == 0) {
#pragma unroll
        for (int o = 0; o < 4; ++o) {
            float s = fcb[o];
            for (int w = 0; w < 8; ++w) s += SM[104 + w * 4 + o];
            SM[96 + o] = s;   // ANG
        }
    }
    __syncthreads();

    // ---- 4-qubit statevector sim (wave 0) ----
    if (tid < 64) {
        const int s = tid & 15;
        float re = (s == 0) ? 1.f : 0.f, im = 0.f;
#pragma unroll
        for (int w = 0; w < 4; ++w) {
            float a = SM[96 + w] * 0.5f;
            float sn, c; sincosf(a, &sn, &c);
            int stride = 1 << (3 - w);
            float pr = __shfl_xor(re, stride);
            float pi = __shfl_xor(im, stride);
            float nre = c * re + sn * pi;
            float nim = c * im - sn * pr;
            re = nre; im = nim;
        }
#pragma unroll
        for (int l = 0; l < 3; ++l) {
#pragma unroll
            for (int w = 0; w < 4; ++w) {
                const float* U = ROT + (l * 4 + w) * 8;
                int stride = 1 << (3 - w);
                bool bit = (s & stride) != 0;
                float pr = __shfl_xor(re, stride);
                float pi = __shfl_xor(im, stride);
                float cAr = bit ? U[6] : U[0], cAi = bit ? U[7] : U[1];
                float cBr = bit ? U[4] : U[2], cBi = bit ? U[5] : U[3];
                float nre = cAr * re - cAi * im + cBr * pr - cBi * pi;
                float nim = cAr * im + cAi * re + cBr * pi + cBi * pr;
                re = nre; im = nim;
            }
            const int r = (l % 3) + 1;
#pragma unroll
            for (int w = 0; w < 4; ++w) {
                int cs = 1 << (3 - w);
                int ts = 1 << (3 - ((w + r) & 3));
                float pr = __shfl_xor(re, ts);
                float pi = __shfl_xor(im, ts);
                if (s & cs) { re = pr; im = pi; }
            }
        }
        float pprob = re * re + im * im;
        float ev[4];
#pragma unroll
        for (int w = 0; w < 4; ++w)
            ev[w] = (s & (1 << (3 - w))) ? -pprob : pprob;
#pragma unroll
        for (int m = 1; m <= 8; m <<= 1)
#pragma unroll
            for (int w = 0; w < 4; ++w)
                ev[w] += __shfl_xor(ev[w], m);
        if (tid == 0) {
#pragma unroll
            for (int w = 0; w < 4; ++w) SM[100 + w] = ev[w];
        }
    }
    __syncthreads();

    const float qv[5] = {SM[100], SM[101], SM[102], SM[103], 1.f};

    // ---- decoder: h4 halves from rank-5 basis, dconv2 partials ----
    float acc3[2][3];
#pragma unroll
    for (int pp = 0; pp < 2; ++pp)
#pragma unroll
        for (int oc = 0; oc < 3; ++oc) acc3[pp][oc] = d2b[oc];

#pragma unroll
    for (int h = 0; h < 2; ++h) {
#pragma unroll
        for (int pp = 0; pp < 2; ++pp) {
            const int p = tid + pp * T;
            const int ibs = ((py0 + pp * 16) + 1) * 34 + (px + 1);
#pragma unroll
            for (int gg = 0; gg < 2; ++gg) {
                const int g = h * 2 + gg;
                float4 a = z4;
#pragma unroll
                for (int j = 0; j < 5; ++j) {
                    const float4 zv = *reinterpret_cast<const float4*>(
                        ws + ((g * 5 + j) * 1024 + p) * 4);
                    a.x = fmaf(qv[j], zv.x, a.x);
                    a.y = fmaf(qv[j], zv.y, a.y);
                    a.z = fmaf(qv[j], zv.z, a.z);
                    a.w = fmaf(qv[j], zv.w, a.w);
                }
                BQ[gg * PS + ibs] = make_float4(fmaxf(a.x, 0.f), fmaxf(a.y, 0.f),
                                                fmaxf(a.z, 0.f), fmaxf(a.w, 0.f));
            }
        }
        __syncthreads();
#pragma unroll
        for (int pp = 0; pp < 2; ++pp) {
            const int wb = (py0 + pp * 16) * 34 + px;
            conv_q4<3, 144>(BQ + wb,      d2w + (h * 8 + 0) * 9, acc3[pp]);
            conv_q4<3, 144>(BQ + PS + wb, d2w + (h * 8 + 4) * 9, acc3[pp]);
        }
        if (h == 0) __syncthreads();   // protect half1's BQ overwrite
    }

    // ---- sigmoid -> out (both pixels) ----
#pragma unroll
    for (int pp = 0; pp < 2; ++pp) {
        float* ob = out + b * 3072 + tid + pp * T;
#pragma unroll
        for (int oc = 0; oc < 3; ++oc)
            ob[oc * 1024] = 1.f / (1.f + expf(-acc3[pp][oc]));
    }
}

// ---------------- launch ----------------------------------------------------
extern "C" void kernel_launch(void* const* d_in, const int* in_sizes, int n_in,
                              void* d_out, int out_size, void* d_ws, size_t ws_size,
                              hipStream_t stream) {
    const float* x   = (const float*)d_in[0];
    const float* c1w = (const float*)d_in[1];
    const float* c1b = (const float*)d_in[2];
    const float* c2w = (const float*)d_in[3];
    const float* c2b = (const float*)d_in[4];
    const float* fcw = (const float*)d_in[5];
    const float* fcb = (const float*)d_in[6];
    const float* qw  = (const float*)d_in[7];
    const float* f2w = (const float*)d_in[8];
    const float* f2b = (const float*)d_in[9];
    const float* d1w = (const float*)d_in[10];
    const float* d1b = (const float*)d_in[11];
    const float* d2w = (const float*)d_in[12];
    const float* d2b = (const float*)d_in[13];
    float* out = (float*)d_out;
    float* ws  = (float*)d_ws;

    prep_z_kernel<<<5, TP, 0, stream>>>(f2w, f2b, d1w, d1b, ws);
    prep_fcwt_kernel<<<8, TP, 0, stream>>>(fcw, ws + ZSZ);
    fused_kernel<<<2048, T, 0, stream>>>(
        x, c1w, c1b, c2w, c2b, fcb, qw, d2w, d2b, ws, out);
}

// Round 11
// 295.531 us; speedup vs baseline: 1.6899x; 1.6899x over previous
//
#include <hip/hip_runtime.h>
#include <math.h>

#define T  1024
#define PS 1156                    // 34*34 plane

#define ZSZ (4 * 5 * 1024 * 4)     // Z[quad g][j][pix] as float4 (floats)
// fcwT at ws + ZSZ: 8192 float4. total ws = 448 KB

// ---- scalar conv accumulate (known-good codegen) ----
template <int NIC, int NOC, int WSTR>
__device__ __forceinline__ void conv_acc(const float* __restrict__ ib,
                                         const float* __restrict__ wg,
                                         float* __restrict__ acc) {
#pragma unroll 2
    for (int ic = 0; ic < NIC; ++ic) {
        float v[9];
#pragma unroll
        for (int ky = 0; ky < 3; ++ky)
#pragma unroll
            for (int kx = 0; kx < 3; ++kx)
                v[ky * 3 + kx] = ib[ic * PS + ky * 34 + kx];
#pragma unroll
        for (int oc = 0; oc < NOC; ++oc) {
            const float* wp = wg + oc * WSTR + ic * 9;
#pragma unroll
            for (int k = 0; k < 9; ++k)
                acc[oc] = fmaf(wp[k], v[k], acc[oc]);
        }
    }
}

// ---- channel-quad conv accumulate: 4 channels in float4 lanes, NOC outputs ----
template <int NOC, int WSTR>
__device__ __forceinline__ void conv_q4(const float4* __restrict__ ib,
                                        const float* __restrict__ wg,
                                        float* __restrict__ acc) {
#pragma unroll
    for (int ky = 0; ky < 3; ++ky) {
        const float4 r0 = ib[ky * 34 + 0];
        const float4 r1 = ib[ky * 34 + 1];
        const float4 r2 = ib[ky * 34 + 2];
#pragma unroll
        for (int oc = 0; oc < NOC; ++oc) {
            const float* wp = wg + oc * WSTR + ky * 3;   // uniform -> s_load
            float s = acc[oc];
            s = fmaf(wp[0],  r0.x, s); s = fmaf(wp[1],  r1.x, s); s = fmaf(wp[2],  r2.x, s);
            s = fmaf(wp[9],  r0.y, s); s = fmaf(wp[10], r1.y, s); s = fmaf(wp[11], r2.y, s);
            s = fmaf(wp[18], r0.z, s); s = fmaf(wp[19], r1.z, s); s = fmaf(wp[20], r2.z, s);
            s = fmaf(wp[27], r0.w, s); s = fmaf(wp[28], r1.w, s); s = fmaf(wp[29], r2.w, s);
            acc[oc] = s;
        }
    }
}

// ---- prep 1: decoder basis Z[g][j][pix] = conv3x3(F_j, d1w) (+d1b for j=4) ----
__global__ __launch_bounds__(T) void prep_z_kernel(
    const float* __restrict__ f2w, const float* __restrict__ f2b,
    const float* __restrict__ d1w, const float* __restrict__ d1b,
    float* __restrict__ ws) {
    __shared__ float F[8 * PS];
    const int tid = threadIdx.x;
    const int j = blockIdx.x;                 // 0..4 (4 = bias basis)
    const int py = tid >> 5, px = tid & 31;
    const int wbase = py * 34 + px;
    const int ibase = (py + 1) * 34 + (px + 1);

    for (int i = tid; i < 8 * PS; i += T) F[i] = 0.f;
    __syncthreads();
#pragma unroll
    for (int c = 0; c < 8; ++c) {
        const int idx = c * 1024 + tid;
        F[c * PS + ibase] = (j < 4) ? f2w[idx * 4 + j] : f2b[idx];
    }
    __syncthreads();
    float a1[16];
#pragma unroll
    for (int oc = 0; oc < 16; ++oc) a1[oc] = (j == 4) ? d1b[oc] : 0.f;
    conv_acc<8, 16, 72>(F + wbase, d1w, a1);
#pragma unroll
    for (int g = 0; g < 4; ++g) {
        float4 v = make_float4(a1[4 * g], a1[4 * g + 1], a1[4 * g + 2], a1[4 * g + 3]);
        *reinterpret_cast<float4*>(ws + ((g * 5 + j) * 1024 + tid) * 4) = v;
    }
}

// ---- prep 2: fcwT[gj] = float4{fcw[o*8192+gj]} ----
__global__ __launch_bounds__(T) void prep_fcwt_kernel(
    const float* __restrict__ fcw, float* __restrict__ fcwT) {
    const int i = blockIdx.x * T + threadIdx.x;
#pragma unroll
    for (int o = 0; o < 4; ++o)
        fcwT[i * 4 + o] = fcw[o * 8192 + i];
}

// ---------------- fused per-image kernel -----------------------------------
// 1px/thread (the proven-safe register shape). LB(1024,4): the one bound that
// does not force spills (allocator budget ~64). sched_barrier(0) between the
// two conv_q4 calls caps live window regs at one quad (12 floats) -> target
// alloc <= 56 so TWO 16-wave blocks co-reside (HW halves waves at alloc>=64).
// LDS: XS 13.9KB + BQ 37KB + SM = 51.5KB -> 2 blocks = 103KB <= 160KB.
__global__ __launch_bounds__(T, 4) void fused_kernel(
    const float* __restrict__ x,
    const float* __restrict__ c1w, const float* __restrict__ c1b,
    const float* __restrict__ c2w, const float* __restrict__ c2b,
    const float* __restrict__ fcb,
    const float* __restrict__ qw,
    const float* __restrict__ d2w, const float* __restrict__ d2b,
    const float* __restrict__ ws,
    float* __restrict__ out) {
    __shared__ float  XS[3 * PS];     // x, scalar planes (conv1 is cheap)
    __shared__ float4 BQ[2 * PS];     // h1/h4 channel-quad halves
    __shared__ float  SM[168];        // ROT 96 | ANG 4 | Q 4 | RED 64
    float* ROT = SM;
    const float* fcwT = ws + ZSZ;

    const int tid = threadIdx.x;
    const int b   = blockIdx.x;
    const int py  = tid >> 5, px = tid & 31;
    const int wbase = py * 34 + px;
    const int ibase = (py + 1) * 34 + (px + 1);

    const float4 z4 = make_float4(0.f, 0.f, 0.f, 0.f);
    for (int i = tid; i < 3 * PS; i += T) XS[i] = 0.f;      // halos must be 0
    for (int i = tid; i < 2 * PS; i += T) BQ[i] = z4;
    if (tid < 168) SM[tid] = 0.f;
    __syncthreads();

    if (tid < 12) {   // Rot matrices (batch-independent, tiny)
        float phi = qw[tid * 3 + 0], theta = qw[tid * 3 + 1], omega = qw[tid * 3 + 2];
        float a = 0.5f * (phi + omega), d = 0.5f * (phi - omega);
        float st, ct; sincosf(0.5f * theta, &st, &ct);
        float sa, ca; sincosf(a, &sa, &ca);
        float sd, cd; sincosf(d, &sd, &cd);
        float* o = ROT + tid * 8;
        o[0] = ct * ca;  o[1] = -ct * sa;
        o[2] = -st * cd; o[3] = -st * sd;
        o[4] = st * cd;  o[5] = -st * sd;
        o[6] = ct * ca;  o[7] = ct * sa;
    }

    // ---- load x (3,32,32) into XS interior ----
    {
        const float* xb = x + b * 3072;
#pragma unroll
        for (int k = 0; k < 3; ++k) {
            int i = tid + k * T;
            int c = i >> 10, p = i & 1023;
            XS[c * PS + ((p >> 5) + 1) * 34 + (p & 31) + 1] = xb[i];
        }
    }
    __syncthreads();

    float acc2[8];
#pragma unroll
    for (int oc = 0; oc < 8; ++oc) acc2[oc] = c2b[oc];
    float part[4] = {0.f, 0.f, 0.f, 0.f};

#pragma unroll
    for (int h = 0; h < 2; ++h) {
        // ---- conv1 half h (oc h*8..h*8+7) -> BQ quads ----
        {
            float a1[8];
#pragma unroll
            for (int oc = 0; oc < 8; ++oc) a1[oc] = c1b[h * 8 + oc];
            conv_acc<3, 8, 27>(XS + wbase, c1w + h * 8 * 27, a1);
            BQ[ibase]      = make_float4(fmaxf(a1[0], 0.f), fmaxf(a1[1], 0.f),
                                         fmaxf(a1[2], 0.f), fmaxf(a1[3], 0.f));
            BQ[PS + ibase] = make_float4(fmaxf(a1[4], 0.f), fmaxf(a1[5], 0.f),
                                         fmaxf(a1[6], 0.f), fmaxf(a1[7], 0.f));
        }
        __syncthreads();
        // ---- conv2 partial over this half's 8 input channels ----
        conv_q4<8, 144>(BQ + wbase, c2w + (h * 8 + 0) * 9, acc2);
        __builtin_amdgcn_sched_barrier(0);   // cap live windows at one quad
        conv_q4<8, 144>(BQ + PS + wbase, c2w + (h * 8 + 4) * 9, acc2);
        __syncthreads();   // before next half overwrites BQ
    }

    // ---- relu + fc fold (float4 fcwT) ----
#pragma unroll
    for (int oc = 0; oc < 8; ++oc) {
        const float hv = fmaxf(acc2[oc], 0.f);
        const float4 wv = *reinterpret_cast<const float4*>(fcwT + (oc * 1024 + tid) * 4);
        part[0] = fmaf(hv, wv.x, part[0]);
        part[1] = fmaf(hv, wv.y, part[1]);
        part[2] = fmaf(hv, wv.z, part[2]);
        part[3] = fmaf(hv, wv.w, part[3]);
    }

    // ---- fc reduce -> angles (16 waves) ----
#pragma unroll
    for (int off = 32; off; off >>= 1)
#pragma unroll
        for (int o = 0; o < 4; ++o)
            part[o] += __shfl_down(part[o], off);
    if ((tid & 63) == 0) {
        int wid = tid >> 6;
#pragma unroll
        for (int o = 0; o < 4; ++o) SM[104 + wid * 4 + o] = part[o];
    }
    __syncthreads();
    if (tid == 0) {
#pragma unroll
        for (int o = 0; o < 4; ++o) {
            float s = fcb[o];
            for (int w = 0; w < 16; ++w) s += SM[104 + w * 4 + o];
            SM[96 + o] = s;   // ANG
        }
    }
    __syncthreads();

    // ---- 4-qubit statevector sim (wave 0) ----
    if (tid < 64) {
        const int s = tid & 15;
        float re = (s == 0) ? 1.f : 0.f, im = 0.f;
#pragma unroll
        for (int w = 0; w < 4; ++w) {
            float a = SM[96 + w] * 0.5f;
            float sn, c; sincosf(a, &sn, &c);
            int stride = 1 << (3 - w);
            float pr = __shfl_xor(re, stride);
            float pi = __shfl_xor(im, stride);
            float nre = c * re + sn * pi;
            float nim = c * im - sn * pr;
            re = nre; im = nim;
        }
#pragma unroll
        for (int l = 0; l < 3; ++l) {
#pragma unroll
            for (int w = 0; w < 4; ++w) {
                const float* U = ROT + (l * 4 + w) * 8;
                int stride = 1 << (3 - w);
                bool bit = (s & stride) != 0;
                float pr = __shfl_xor(re, stride);
                float pi = __shfl_xor(im, stride);
                float cAr = bit ? U[6] : U[0], cAi = bit ? U[7] : U[1];
                float cBr = bit ? U[4] : U[2], cBi = bit ? U[5] : U[3];
                float nre = cAr * re - cAi * im + cBr * pr - cBi * pi;
                float nim = cAr * im + cAi * re + cBr * pi + cBi * pr;
                re = nre; im = nim;
            }
            const int r = (l % 3) + 1;
#pragma unroll
            for (int w = 0; w < 4; ++w) {
                int cs = 1 << (3 - w);
                int ts = 1 << (3 - ((w + r) & 3));
                float pr = __shfl_xor(re, ts);
                float pi = __shfl_xor(im, ts);
                if (s & cs) { re = pr; im = pi; }
            }
        }
        float pprob = re * re + im * im;
        float ev[4];
#pragma unroll
        for (int w = 0; w < 4; ++w)
            ev[w] = (s & (1 << (3 - w))) ? -pprob : pprob;
#pragma unroll
        for (int m = 1; m <= 8; m <<= 1)
#pragma unroll
            for (int w = 0; w < 4; ++w)
                ev[w] += __shfl_xor(ev[w], m);
        if (tid == 0) {
#pragma unroll
            for (int w = 0; w < 4; ++w) SM[100 + w] = ev[w];
        }
    }
    __syncthreads();

    const float qv[5] = {SM[100], SM[101], SM[102], SM[103], 1.f};

    // ---- decoder: h4 halves from rank-5 basis, dconv2 partials ----
    float acc3[3];
#pragma unroll
    for (int oc = 0; oc < 3; ++oc) acc3[oc] = d2b[oc];

#pragma unroll
    for (int h = 0; h < 2; ++h) {
#pragma unroll
        for (int gg = 0; gg < 2; ++gg) {
            const int g = h * 2 + gg;
            float4 a = z4;
#pragma unroll
            for (int j = 0; j < 5; ++j) {
                const float4 zv = *reinterpret_cast<const float4*>(
                    ws + ((g * 5 + j) * 1024 + tid) * 4);
                a.x = fmaf(qv[j], zv.x, a.x);
                a.y = fmaf(qv[j], zv.y, a.y);
                a.z = fmaf(qv[j], zv.z, a.z);
                a.w = fmaf(qv[j], zv.w, a.w);
            }
            BQ[gg * PS + ibase] = make_float4(fmaxf(a.x, 0.f), fmaxf(a.y, 0.f),
                                              fmaxf(a.z, 0.f), fmaxf(a.w, 0.f));
        }
        __syncthreads();
        conv_q4<3, 144>(BQ + wbase, d2w + (h * 8 + 0) * 9, acc3);
        __builtin_amdgcn_sched_barrier(0);
        conv_q4<3, 144>(BQ + PS + wbase, d2w + (h * 8 + 4) * 9, acc3);
        if (h == 0) __syncthreads();   // protect half1's BQ overwrite
    }

    // ---- sigmoid -> out ----
    {
        float* ob = out + b * 3072 + tid;
#pragma unroll
        for (int oc = 0; oc < 3; ++oc)
            ob[oc * 1024] = 1.f / (1.f + expf(-acc3[oc]));
    }
}

// ---------------- launch ----------------------------------------------------
extern "C" void kernel_launch(void* const* d_in, const int* in_sizes, int n_in,
                              void* d_out, int out_size, void* d_ws, size_t ws_size,
                              hipStream_t stream) {
    const float* x   = (const float*)d_in[0];
    const float* c1w = (const float*)d_in[1];
    const float* c1b = (const float*)d_in[2];
    const float* c2w = (const float*)d_in[3];
    const float* c2b = (const float*)d_in[4];
    const float* fcw = (const float*)d_in[5];
    const float* fcb = (const float*)d_in[6];
    const float* qw  = (const float*)d_in[7];
    const float* f2w = (const float*)d_in[8];
    const float* f2b = (const float*)d_in[9];
    const float* d1w = (const float*)d_in[10];
    const float* d1b = (const float*)d_in[11];
    const float* d2w = (const float*)d_in[12];
    const float* d2b = (const float*)d_in[13];
    float* out = (float*)d_out;
    float* ws  = (float*)d_ws;

    prep_z_kernel<<<5, T, 0, stream>>>(f2w, f2b, d1w, d1b, ws);
    prep_fcwt_kernel<<<8, T, 0, stream>>>(fcw, ws + ZSZ);
    fused_kernel<<<2048, T, 0, stream>>>(
        x, c1w, c1b, c2w, c2b, fcb, qw, d2w, d2b, ws, out);
}